// Round 9
// baseline (384.909 us; speedup 1.0000x reference)
//
#include <hip/hip_runtime.h>
#include <hip/hip_bf16.h>

// ---- problem constants ----
#define B_     16
#define NBAND  4
#define HP     56
#define WP     56
#define C_     96
#define NHEADS 3
#define HD     32
#define NT     196                 // tokens per window
#define NTP    224                 // padded to 14x16
#define BW     1024                // windows
#define HID    384
#define NTOK   200704

typedef unsigned short u16;
typedef short s16;
typedef __attribute__((ext_vector_type(8))) s16   short8_t;  // 8 bf16 (4 VGPR)
typedef __attribute__((ext_vector_type(4))) s16   short4_t;
typedef __attribute__((ext_vector_type(4))) float f32x4;

__device__ __forceinline__ float bf2f(u16 u) {
    union { float f; unsigned int i; } x; x.i = ((unsigned int)u) << 16; return x.f;
}
__device__ __forceinline__ u16 f2bf(float f) {
    union { float f; unsigned int i; } x; x.f = f;
    unsigned int r = x.i + 0x7fffu + ((x.i >> 16) & 1u);
    return (u16)(r >> 16);
}
// exact-GELU via A&S 7.1.26 erf approximation (max err 1.5e-7)
__device__ __forceinline__ float gelu_f(float a) {
    float x  = a * 0.70710678118654752f;
    float ax = fabsf(x);
    float t  = 1.0f / (1.0f + 0.3275911f * ax);
    float poly = t * (0.254829592f + t * (-0.284496736f +
                 t * (1.421413741f + t * (-1.453152027f + t * 1.061405429f))));
    float e  = 1.0f - poly * __expf(-x * x);
    float er = copysignf(e, x);
    return 0.5f * a * (1.0f + er);
}

// ---- workspace layout (bf16 elements) ----
#define WT_OFF   0          // qkv_w^T  [288][96]
#define PJT_OFF  27648      // proj_w^T [96][96]
#define F1T_OFF  36864      // fc1_w^T  [384][96]
#define F2T_OFF  73728      // fc2_w^T  [96][384]
#define WS_ELEMS 110592     // * 2 bytes = 221,184 B

__global__ __launch_bounds__(256) void setup_kernel(
    const float* __restrict__ qkv_w, const float* __restrict__ proj_w,
    const float* __restrict__ fc1_w, const float* __restrict__ fc2_w,
    u16* __restrict__ ws)
{
    int i0 = blockIdx.x * 256 + threadIdx.x;
    int stride = gridDim.x * 256;
    for (int e = i0; e < 27648; e += stride) {          // wT[n][k] = qkv_w[k][n]
        int n = e / 96, k = e - n * 96;
        ws[WT_OFF + e] = f2bf(qkv_w[k * 288 + n]);
    }
    for (int e = i0; e < 9216; e += stride) {           // pjT[n][k]
        int n = e / 96, k = e - n * 96;
        ws[PJT_OFF + e] = f2bf(proj_w[k * 96 + n]);
    }
    for (int e = i0; e < 36864; e += stride) {          // f1T[n][k], n<384
        int n = e / 96, k = e - n * 96;
        ws[F1T_OFF + e] = f2bf(fc1_w[k * 384 + n]);
    }
    for (int e = i0; e < 36864; e += stride) {          // f2T[n][k], n<96, k<384
        int n = e / 384, k = e - n * 384;
        ws[F2T_OFF + e] = f2bf(fc2_w[k * 96 + n]);
    }
}

// =====================================================================
// MFMA attention kernel: one block per window, 7 waves (448 thr).
// Q routed through the per-wave Stg buffer (no Qs), single Stg buffer
// (no ping-pong). LDS ~42.5KB -> 2 blocks/CU.
// =====================================================================
#define NWV    7
#define QK_LD  40    // K row stride (u16): 80B -> 2-way bank alias (free)
#define VT_LD  232   // V^T row stride
#define STG_LD 40    // per-wave staging row stride

__global__ __launch_bounds__(448) void attn_mfma_kernel(
    const float* __restrict__ x,
    const u16*  __restrict__ ws,
    const float* __restrict__ qkv_b,
    const float* __restrict__ proj_b,
    float* __restrict__ out)
{
    __shared__ __align__(16) u16 Ks[NTP * QK_LD];        // 17,920 B
    __shared__ __align__(16) u16 VTs[HD * VT_LD];        // 14,848 B
    __shared__ __align__(16) u16 Stg[NWV * 16 * STG_LD]; //  8,960 B (per-wave)
    __shared__ int rowsL[NT];

    const int wi  = blockIdx.x;
    const int b   = wi >> 6, ih = (wi >> 3) & 7, iw = wi & 7;
    const int tid = threadIdx.x;
    const int w   = tid >> 6, lane = tid & 63;
    const int l15 = lane & 15, g = lane >> 4;

    // token t=(n,r,col) -> flat row; roll(-3) gather == roll(+3) scatter
    if (tid < NT) {
        int t = tid;
        int n = t / 49, rc = t - n * 49, r = rc / 7, cl = rc - r * 7;
        int hh = ih * 7 + r  + 3; if (hh >= HP) hh -= HP;
        int ww = iw * 7 + cl + 3; if (ww >= WP) ww -= WP;
        rowsL[t] = ((b * NBAND + n) * HP + hh) * WP + ww;
    }
    __syncthreads();

    const u16* wT  = ws + WT_OFF;
    const u16* pjT = ws + PJT_OFF;

    // ---- preload x A-fragments for both owned M-tiles (head-invariant) ----
    short8_t ax[2][3];
    #pragma unroll
    for (int im = 0; im < 2; ++im) {
        int mt = w + NWV * im;
        int t  = mt * 16 + l15;
        bool valid = (t < NT);
        const float* xb = x + (valid ? (size_t)rowsL[t] * C_ : 0);
        #pragma unroll
        for (int ks = 0; ks < 3; ++ks) {
            short8_t a;
            if (valid) {
                const float* p = xb + ks * 32 + g * 8;
                #pragma unroll
                for (int j = 0; j < 8; ++j) a[j] = (s16)f2bf(p[j]);
            } else {
                #pragma unroll
                for (int j = 0; j < 8; ++j) a[j] = 0;
            }
            ax[im][ks] = a;
        }
    }

    f32x4 po[2][6];                       // proj accumulators
    #pragma unroll
    for (int im = 0; im < 2; ++im)
        #pragma unroll
        for (int nj = 0; nj < 6; ++nj)
            po[im][nj] = (f32x4){0.f, 0.f, 0.f, 0.f};

    u16* const st0 = Stg + w * (16 * STG_LD);

    for (int h = 0; h < NHEADS; ++h) {
        short8_t aQ2[2];
        // ---- QKV GEMM for head h; Q transposed via per-wave Stg ----
        #pragma unroll
        for (int im = 0; im < 2; ++im) {
            int mt = w + NWV * im;
            int trow = mt * 16 + 4 * g;
            // Q halves -> Stg (C-layout), then read A-layout fragment
            #pragma unroll
            for (int nh = 0; nh < 2; ++nh) {
                int ncol = h * 32 + nh * 16 + l15;
                f32x4 acc = {0.f, 0.f, 0.f, 0.f};
                #pragma unroll
                for (int ks = 0; ks < 3; ++ks) {
                    short8_t bw = *(const short8_t*)(wT + ncol * 96 + ks * 32 + g * 8);
                    acc = __builtin_amdgcn_mfma_f32_16x16x32_bf16(ax[im][ks], bw, acc, 0, 0, 0);
                }
                float bias = qkv_b[ncol];
                const float sc = 0.17677669529663687f;      // hd^-0.5 folded into Q
                #pragma unroll
                for (int r = 0; r < 4; ++r)
                    st0[(4 * g + r) * STG_LD + nh * 16 + l15] = f2bf((acc[r] + bias) * sc);
            }
            aQ2[im] = *(const short8_t*)(st0 + l15 * STG_LD + g * 8);
            // K halves -> Ks
            #pragma unroll
            for (int nh = 0; nh < 2; ++nh) {
                int ncol = 96 + h * 32 + nh * 16 + l15;
                f32x4 acc = {0.f, 0.f, 0.f, 0.f};
                #pragma unroll
                for (int ks = 0; ks < 3; ++ks) {
                    short8_t bw = *(const short8_t*)(wT + ncol * 96 + ks * 32 + g * 8);
                    acc = __builtin_amdgcn_mfma_f32_16x16x32_bf16(ax[im][ks], bw, acc, 0, 0, 0);
                }
                float bias = qkv_b[ncol];
                int d = nh * 16 + l15;
                #pragma unroll
                for (int r = 0; r < 4; ++r)
                    Ks[(trow + r) * QK_LD + d] = f2bf(acc[r] + bias);
            }
            // V halves -> VTs (transposed, b64 row-writes)
            #pragma unroll
            for (int nh = 0; nh < 2; ++nh) {
                int ncol = 192 + h * 32 + nh * 16 + l15;
                f32x4 acc = {0.f, 0.f, 0.f, 0.f};
                #pragma unroll
                for (int ks = 0; ks < 3; ++ks) {
                    short8_t bw = *(const short8_t*)(wT + ncol * 96 + ks * 32 + g * 8);
                    acc = __builtin_amdgcn_mfma_f32_16x16x32_bf16(ax[im][ks], bw, acc, 0, 0, 0);
                }
                float bias = qkv_b[ncol];
                int d = nh * 16 + l15;
                short4_t v4;
                #pragma unroll
                for (int r = 0; r < 4; ++r) v4[r] = (s16)f2bf(acc[r] + bias);
                *(short4_t*)(VTs + d * VT_LD + trow) = v4;
            }
        }
        __syncthreads();

        // ---- attention + per-head proj accumulate ----
        #pragma unroll
        for (int im = 0; im < 2; ++im) {
            int mt = w + NWV * im;
            short8_t aQ = aQ2[im];
            f32x4 s[13];
            #pragma unroll
            for (int kt = 0; kt < 13; ++kt) {
                short8_t bK = *(const short8_t*)(Ks + (kt * 16 + l15) * QK_LD + g * 8);
                f32x4 z = {0.f, 0.f, 0.f, 0.f};
                s[kt] = __builtin_amdgcn_mfma_f32_16x16x32_bf16(aQ, bK, z, 0, 0, 0);
            }
            if (l15 >= 4) {                   // keys 192+l15 >= 196 invalid
                #pragma unroll
                for (int r = 0; r < 4; ++r) s[12][r] = -1e30f;
            }
            float m[4], sum[4];
            #pragma unroll
            for (int r = 0; r < 4; ++r) {
                float mm = s[0][r];
                #pragma unroll
                for (int kt = 1; kt < 13; ++kt) mm = fmaxf(mm, s[kt][r]);
                #pragma unroll
                for (int o = 1; o < 16; o <<= 1) mm = fmaxf(mm, __shfl_xor(mm, o, 64));
                m[r] = mm;
                sum[r] = 0.f;
            }

            // PV chunked: per kp stage 16x32 of P (single buffer, in-order DS)
            f32x4 o0 = {0.f,0.f,0.f,0.f}, o1 = {0.f,0.f,0.f,0.f};
            #pragma unroll
            for (int kp = 0; kp < 7; ++kp) {
                #pragma unroll
                for (int r = 0; r < 4; ++r) {
                    float p0 = __expf(s[2 * kp][r] - m[r]);
                    sum[r] += p0;
                    st0[(4 * g + r) * STG_LD + l15] = f2bf(p0);
                    if (kp < 6) {
                        float p1 = __expf(s[2 * kp + 1][r] - m[r]);
                        sum[r] += p1;
                        st0[(4 * g + r) * STG_LD + 16 + l15] = f2bf(p1);
                    } else {
                        st0[(4 * g + r) * STG_LD + 16 + l15] = 0;   // padded keys
                    }
                }
                short8_t aP  = *(const short8_t*)(st0 + l15 * STG_LD + g * 8);
                short8_t bV0 = *(const short8_t*)(VTs + l15 * VT_LD + kp * 32 + g * 8);
                short8_t bV1 = *(const short8_t*)(VTs + (16 + l15) * VT_LD + kp * 32 + g * 8);
                o0 = __builtin_amdgcn_mfma_f32_16x16x32_bf16(aP, bV0, o0, 0, 0, 0);
                o1 = __builtin_amdgcn_mfma_f32_16x16x32_bf16(aP, bV1, o1, 0, 0, 0);
            }
            #pragma unroll
            for (int r = 0; r < 4; ++r) {
                #pragma unroll
                for (int o = 1; o < 16; o <<= 1) sum[r] += __shfl_xor(sum[r], o, 64);
            }

            // normalize, stage O chunk, accumulate proj k-slice for head h
            {
                #pragma unroll
                for (int r = 0; r < 4; ++r) {
                    float inv = 1.f / sum[r];
                    st0[(4 * g + r) * STG_LD + l15]      = f2bf(o0[r] * inv);
                    st0[(4 * g + r) * STG_LD + 16 + l15] = f2bf(o1[r] * inv);
                }
                short8_t aO = *(const short8_t*)(st0 + l15 * STG_LD + g * 8);
                #pragma unroll
                for (int nj = 0; nj < 6; ++nj) {
                    short8_t bw = *(const short8_t*)(pjT + (nj * 16 + l15) * 96 + h * 32 + g * 8);
                    po[im][nj] = __builtin_amdgcn_mfma_f32_16x16x32_bf16(aO, bw, po[im][nj], 0, 0, 0);
                }
            }
        }
        __syncthreads();
    }

    // ---- epilogue: bias + scatter; row-grouped stores ----
    #pragma unroll
    for (int im = 0; im < 2; ++im) {
        int mt = w + NWV * im;
        int trow = mt * 16 + 4 * g;
        #pragma unroll
        for (int r = 0; r < 4; ++r) {
            int t = trow + r;
            if (t < NT) {
                float* orow = out + (size_t)rowsL[t] * C_;
                #pragma unroll
                for (int nj = 0; nj < 6; ++nj)
                    orow[nj * 16 + l15] = po[im][nj][r] + proj_b[nj * 16 + l15];
            }
        }
    }
}

// =====================================================================
// MFMA MLP kernel: round-8 proven 5-phase structure + pipelined B loads;
// xr stored as bf16 (only change) -> LDS ~37.9KB -> 4 blocks/CU.
// =====================================================================
#define XR_LD 104

__global__ __launch_bounds__(256) void mlp_mfma_kernel(
    float* __restrict__ io,
    const u16* __restrict__ ws,
    const float* __restrict__ g1, const float* __restrict__ b1,
    const float* __restrict__ g2, const float* __restrict__ b2,
    const float* __restrict__ fc1_b, const float* __restrict__ fc2_b)
{
    __shared__ __align__(16) u16 xr[64 * XR_LD];        // 13,312 B (x2', bf16)
    __shared__ __align__(16) u16 yb[64 * 104];          // 13,312 B (LN2, bf16)
    __shared__ __align__(16) u16 stage[4 * 2 * 16 * STG_LD];  // 10,240 B
    __shared__ float mu[64], rs[64], mu2[64], rs2[64];

    const int tid = threadIdx.x;
    const int w = tid >> 6, l15 = (tid & 63) & 15, g = (tid & 63) >> 4;
    float* base = io + (size_t)blockIdx.x * 64 * C_;
    const u16* f1T = ws + F1T_OFF;
    const u16* f2T = ws + F2T_OFF;

    for (int i = tid; i < 64 * 96; i += 256) {
        int t = i / 96, c = i - t * 96;
        xr[t * XR_LD + c] = f2bf(base[i]);
    }
    __syncthreads();

    // LN1 stats: 4 lanes per token, 24 elems each
    {
        int t = tid >> 2, q = tid & 3;
        const u16* row = xr + t * XR_LD + q * 24;
        float s1 = 0.f, s2 = 0.f;
        #pragma unroll
        for (int j = 0; j < 24; ++j) { float v = bf2f(row[j]); s1 += v; s2 += v * v; }
        s1 += __shfl_xor(s1, 1); s2 += __shfl_xor(s2, 1);
        s1 += __shfl_xor(s1, 2); s2 += __shfl_xor(s2, 2);
        if (q == 0) {
            float m_ = s1 * (1.f / 96.f);
            mu[t] = m_;
            rs[t] = rsqrtf(s2 * (1.f / 96.f) - m_ * m_ + 1e-5f);
        }
    }
    __syncthreads();
    // x2' = x2 + LN1(x2)
    for (int i = tid; i < 64 * 96; i += 256) {
        int t = i / 96, c = i - t * 96;
        float v = bf2f(xr[t * XR_LD + c]);
        xr[t * XR_LD + c] = f2bf(v + (v - mu[t]) * rs[t] * g1[c] + b1[c]);
    }
    __syncthreads();
    // LN2 stats
    {
        int t = tid >> 2, q = tid & 3;
        const u16* row = xr + t * XR_LD + q * 24;
        float s1 = 0.f, s2 = 0.f;
        #pragma unroll
        for (int j = 0; j < 24; ++j) { float v = bf2f(row[j]); s1 += v; s2 += v * v; }
        s1 += __shfl_xor(s1, 1); s2 += __shfl_xor(s2, 1);
        s1 += __shfl_xor(s1, 2); s2 += __shfl_xor(s2, 2);
        if (q == 0) {
            float m_ = s1 * (1.f / 96.f);
            mu2[t] = m_;
            rs2[t] = rsqrtf(s2 * (1.f / 96.f) - m_ * m_ + 1e-5f);
        }
    }
    __syncthreads();
    for (int i = tid; i < 64 * 96; i += 256) {
        int t = i / 96, c = i - t * 96;
        yb[t * 104 + c] = f2bf((bf2f(xr[t * XR_LD + c]) - mu2[t]) * rs2[t] * g2[c] + b2[c]);
    }
    __syncthreads();

    // A-fragments from yb (proven layout)
    short8_t aY[3];
    #pragma unroll
    for (int ks = 0; ks < 3; ++ks)
        aY[ks] = *(const short8_t*)(yb + (w * 16 + l15) * 104 + ks * 32 + g * 8);

    f32x4 po[6];
    #pragma unroll
    for (int nj = 0; nj < 6; ++nj) po[nj] = (f32x4){0.f, 0.f, 0.f, 0.f};

    // ---- B-fragment software pipeline (proven round-8 schedule) ----
    short8_t c1[2][3], n1[2][3], c2[6];
    #pragma unroll
    for (int half = 0; half < 2; ++half)
        #pragma unroll
        for (int k2 = 0; k2 < 3; ++k2)
            c1[half][k2] = *(const short8_t*)(f1T + (half * 16 + l15) * 96 + k2 * 32 + g * 8);

    u16* const st0 = stage + w * (2 * 16 * STG_LD);
    for (int ks = 0; ks < 12; ++ks) {          // fc2 k-step = 2 fc1 N-tiles
        u16* st = st0 + (ks & 1) * (16 * STG_LD);

        #pragma unroll
        for (int nj = 0; nj < 6; ++nj)
            c2[nj] = *(const short8_t*)(f2T + (nj * 16 + l15) * 384 + ks * 32 + g * 8);
        {
            int ksn = (ks < 11) ? ks + 1 : 11;
            #pragma unroll
            for (int half = 0; half < 2; ++half)
                #pragma unroll
                for (int k2 = 0; k2 < 3; ++k2)
                    n1[half][k2] = *(const short8_t*)(f1T + ((ksn * 2 + half) * 16 + l15) * 96 + k2 * 32 + g * 8);
        }

        #pragma unroll
        for (int half = 0; half < 2; ++half) {
            int ncol = (ks * 2 + half) * 16 + l15;
            f32x4 acc = {0.f, 0.f, 0.f, 0.f};
            #pragma unroll
            for (int k2 = 0; k2 < 3; ++k2)
                acc = __builtin_amdgcn_mfma_f32_16x16x32_bf16(aY[k2], c1[half][k2], acc, 0, 0, 0);
            float bias = fc1_b[ncol];
            #pragma unroll
            for (int r = 0; r < 4; ++r)
                st[(4 * g + r) * STG_LD + half * 16 + l15] = f2bf(gelu_f(acc[r] + bias));
        }
        short8_t aH = *(const short8_t*)(st + l15 * STG_LD + g * 8);
        #pragma unroll
        for (int nj = 0; nj < 6; ++nj)
            po[nj] = __builtin_amdgcn_mfma_f32_16x16x32_bf16(aH, c2[nj], po[nj], 0, 0, 0);

        #pragma unroll
        for (int half = 0; half < 2; ++half)
            #pragma unroll
            for (int k2 = 0; k2 < 3; ++k2)
                c1[half][k2] = n1[half][k2];
    }

    // epilogue: residual + bias, row-grouped
    {
        int trow = w * 16 + 4 * g;
        #pragma unroll
        for (int r = 0; r < 4; ++r) {
            int t = trow + r;
            #pragma unroll
            for (int nj = 0; nj < 6; ++nj) {
                int ncol = nj * 16 + l15;
                base[t * 96 + ncol] = bf2f(xr[t * XR_LD + ncol]) + po[nj][r] + fc2_b[ncol];
            }
        }
    }
}

// =====================================================================
extern "C" void kernel_launch(void* const* d_in, const int* in_sizes, int n_in,
                              void* d_out, int out_size, void* d_ws, size_t ws_size,
                              hipStream_t stream)
{
    (void)in_sizes; (void)n_in; (void)out_size; (void)ws_size;

    const float* x      = (const float*)d_in[0];
    const float* qkv_w  = (const float*)d_in[1];
    const float* qkv_b  = (const float*)d_in[2];
    const float* proj_w = (const float*)d_in[3];
    const float* proj_b = (const float*)d_in[4];
    const float* g1     = (const float*)d_in[5];
    const float* b1     = (const float*)d_in[6];
    const float* g2     = (const float*)d_in[7];
    const float* b2     = (const float*)d_in[8];
    const float* fc1_w  = (const float*)d_in[9];
    const float* fc1_b  = (const float*)d_in[10];
    const float* fc2_w  = (const float*)d_in[11];
    const float* fc2_b  = (const float*)d_in[12];
    float* out = (float*)d_out;
    u16* ws = (u16*)d_ws;

    setup_kernel<<<128, 256, 0, stream>>>(qkv_w, proj_w, fc1_w, fc2_w, ws);
    attn_mfma_kernel<<<BW, 448, 0, stream>>>(x, ws, qkv_b, proj_b, out);
    mlp_mfma_kernel<<<NTOK / 64, 256, 0, stream>>>(out, ws, g1, b1, g2, b2, fc1_b, fc2_b);
}

// Round 10
// 342.153 us; speedup vs baseline: 1.1250x; 1.1250x over previous
//
#include <hip/hip_runtime.h>
#include <hip/hip_bf16.h>

// ---- problem constants ----
#define B_     16
#define NBAND  4
#define HP     56
#define WP     56
#define C_     96
#define NHEADS 3
#define HD     32
#define NT     196                 // tokens per window
#define NTP    224                 // padded to 14x16
#define BW     1024                // windows
#define HID    384
#define NTOK   200704

typedef unsigned short u16;
typedef short s16;
typedef __attribute__((ext_vector_type(8))) s16   short8_t;  // 8 bf16 (4 VGPR)
typedef __attribute__((ext_vector_type(4))) s16   short4_t;
typedef __attribute__((ext_vector_type(4))) float f32x4;

__device__ __forceinline__ float bf2f(u16 u) {
    union { float f; unsigned int i; } x; x.i = ((unsigned int)u) << 16; return x.f;
}
// HW RNE conversion (same rounding as manual bit-RNE, ~1 instr vs 4)
__device__ __forceinline__ u16 f2bf(float f) {
    __hip_bfloat16 h = __float2bfloat16(f);
    union { __hip_bfloat16 h; u16 u; } c; c.h = h; return c.u;
}
// sigmoid-GELU: x * sigmoid(1.702x). fc1 pre-activations are ~N(0,0.2)
// here, so |x|<~1 where max approx error < 5e-3; through 0.02-scale fc2
// this contributes ~2e-3 to the output (threshold 6.1e-2).
__device__ __forceinline__ float gelu_f(float a) {
    return __fdividef(a, 1.0f + __expf(-1.702f * a));
}

// ---- workspace layout (bf16 elements) ----
#define WT_OFF   0          // qkv_w^T  [288][96]
#define PJT_OFF  27648      // proj_w^T [96][96]
#define F1T_OFF  36864      // fc1_w^T  [384][96]
#define F2T_OFF  73728      // fc2_w^T  [96][384]
#define WS_ELEMS 110592     // * 2 bytes = 221,184 B

__global__ __launch_bounds__(256) void setup_kernel(
    const float* __restrict__ qkv_w, const float* __restrict__ proj_w,
    const float* __restrict__ fc1_w, const float* __restrict__ fc2_w,
    u16* __restrict__ ws)
{
    int i0 = blockIdx.x * 256 + threadIdx.x;
    int stride = gridDim.x * 256;
    for (int e = i0; e < 27648; e += stride) {          // wT[n][k] = qkv_w[k][n]
        int n = e / 96, k = e - n * 96;
        ws[WT_OFF + e] = f2bf(qkv_w[k * 288 + n]);
    }
    for (int e = i0; e < 9216; e += stride) {           // pjT[n][k]
        int n = e / 96, k = e - n * 96;
        ws[PJT_OFF + e] = f2bf(proj_w[k * 96 + n]);
    }
    for (int e = i0; e < 36864; e += stride) {          // f1T[n][k], n<384
        int n = e / 96, k = e - n * 96;
        ws[F1T_OFF + e] = f2bf(fc1_w[k * 384 + n]);
    }
    for (int e = i0; e < 36864; e += stride) {          // f2T[n][k], n<96, k<384
        int n = e / 384, k = e - n * 384;
        ws[F2T_OFF + e] = f2bf(fc2_w[k * 96 + n]);
    }
}

// =====================================================================
// MFMA attention kernel: one block per window, 7 waves (448 thr)
// (round-8 proven structure; only f2bf implementation swapped)
// =====================================================================
#define NWV    7
#define QK_LD  40    // Q/K row stride (u16): 80B -> 2-way bank alias (free)
#define VT_LD  232   // V^T row stride
#define STG_LD 40    // per-wave staging row stride

__global__ __launch_bounds__(448) void attn_mfma_kernel(
    const float* __restrict__ x,
    const u16*  __restrict__ ws,
    const float* __restrict__ qkv_b,
    const float* __restrict__ proj_b,
    float* __restrict__ out)
{
    __shared__ __align__(16) u16 Qs[NTP * QK_LD];          // 17,920 B
    __shared__ __align__(16) u16 Ks[NTP * QK_LD];          // 17,920 B
    __shared__ __align__(16) u16 VTs[HD * VT_LD];          // 14,848 B
    __shared__ __align__(16) u16 Stg[NWV * 2 * 16 * STG_LD]; // 17,920 B
    __shared__ int rowsL[NT];

    const int wi  = blockIdx.x;
    const int b   = wi >> 6, ih = (wi >> 3) & 7, iw = wi & 7;
    const int tid = threadIdx.x;
    const int w   = tid >> 6, lane = tid & 63;
    const int l15 = lane & 15, g = lane >> 4;

    // token t=(n,r,col) -> flat row; roll(-3) gather == roll(+3) scatter
    if (tid < NT) {
        int t = tid;
        int n = t / 49, rc = t - n * 49, r = rc / 7, cl = rc - r * 7;
        int hh = ih * 7 + r  + 3; if (hh >= HP) hh -= HP;
        int ww = iw * 7 + cl + 3; if (ww >= WP) ww -= WP;
        rowsL[t] = ((b * NBAND + n) * HP + hh) * WP + ww;
    }
    __syncthreads();

    const u16* wT  = ws + WT_OFF;
    const u16* pjT = ws + PJT_OFF;

    // ---- preload x A-fragments for both owned M-tiles (head-invariant) ----
    short8_t ax[2][3];
    #pragma unroll
    for (int im = 0; im < 2; ++im) {
        int mt = w + NWV * im;
        int t  = mt * 16 + l15;
        bool valid = (t < NT);
        const float* xb = x + (valid ? (size_t)rowsL[t] * C_ : 0);
        #pragma unroll
        for (int ks = 0; ks < 3; ++ks) {
            short8_t a;
            if (valid) {
                const float* p = xb + ks * 32 + g * 8;
                #pragma unroll
                for (int j = 0; j < 8; ++j) a[j] = (s16)f2bf(p[j]);
            } else {
                #pragma unroll
                for (int j = 0; j < 8; ++j) a[j] = 0;
            }
            ax[im][ks] = a;
        }
    }

    f32x4 po[2][6];                       // proj accumulators
    #pragma unroll
    for (int im = 0; im < 2; ++im)
        #pragma unroll
        for (int nj = 0; nj < 6; ++nj)
            po[im][nj] = (f32x4){0.f, 0.f, 0.f, 0.f};

    u16* const st0 = Stg + w * (2 * 16 * STG_LD);

    for (int h = 0; h < NHEADS; ++h) {
        // ---- QKV GEMM for head h ----
        #pragma unroll
        for (int im = 0; im < 2; ++im) {
            int mt = w + NWV * im;
            #pragma unroll
            for (int nj = 0; nj < 6; ++nj) {
                int mat = nj >> 1, nh = nj & 1;
                int ncol = mat * 96 + h * 32 + nh * 16 + l15;
                f32x4 acc = {0.f, 0.f, 0.f, 0.f};
                #pragma unroll
                for (int ks = 0; ks < 3; ++ks) {
                    short8_t bw = *(const short8_t*)(wT + ncol * 96 + ks * 32 + g * 8);
                    acc = __builtin_amdgcn_mfma_f32_16x16x32_bf16(ax[im][ks], bw, acc, 0, 0, 0);
                }
                float bias = qkv_b[ncol];
                int d    = nh * 16 + l15;
                int trow = mt * 16 + 4 * g;
                if (mat == 0) {
                    const float sc = 0.17677669529663687f;      // hd^-0.5 folded into Q
                    #pragma unroll
                    for (int r = 0; r < 4; ++r)
                        Qs[(trow + r) * QK_LD + d] = f2bf((acc[r] + bias) * sc);
                } else if (mat == 1) {
                    #pragma unroll
                    for (int r = 0; r < 4; ++r)
                        Ks[(trow + r) * QK_LD + d] = f2bf(acc[r] + bias);
                } else {                       // V stored transposed, b64 row-writes
                    short4_t v4;
                    #pragma unroll
                    for (int r = 0; r < 4; ++r) v4[r] = (s16)f2bf(acc[r] + bias);
                    *(short4_t*)(VTs + d * VT_LD + trow) = v4;
                }
            }
        }
        __syncthreads();

        // ---- attention + per-head proj accumulate ----
        #pragma unroll
        for (int im = 0; im < 2; ++im) {
            int mt = w + NWV * im;
            short8_t aQ = *(const short8_t*)(Qs + (mt * 16 + l15) * QK_LD + g * 8);
            f32x4 s[13];
            #pragma unroll
            for (int kt = 0; kt < 13; ++kt) {
                short8_t bK = *(const short8_t*)(Ks + (kt * 16 + l15) * QK_LD + g * 8);
                f32x4 z = {0.f, 0.f, 0.f, 0.f};
                s[kt] = __builtin_amdgcn_mfma_f32_16x16x32_bf16(aQ, bK, z, 0, 0, 0);
            }
            if (l15 >= 4) {                   // keys 192+l15 >= 196 invalid
                #pragma unroll
                for (int r = 0; r < 4; ++r) s[12][r] = -1e30f;
            }
            float m[4], sum[4];
            #pragma unroll
            for (int r = 0; r < 4; ++r) {
                float mm = s[0][r];
                #pragma unroll
                for (int kt = 1; kt < 13; ++kt) mm = fmaxf(mm, s[kt][r]);
                #pragma unroll
                for (int o = 1; o < 16; o <<= 1) mm = fmaxf(mm, __shfl_xor(mm, o, 64));
                m[r] = mm;
                sum[r] = 0.f;
            }

            // PV chunked: per kp stage 16x32 of P, read A-frag, 2 MFMA
            f32x4 o0 = {0.f,0.f,0.f,0.f}, o1 = {0.f,0.f,0.f,0.f};
            #pragma unroll
            for (int kp = 0; kp < 7; ++kp) {
                u16* st = st0 + (kp & 1) * (16 * STG_LD);
                #pragma unroll
                for (int r = 0; r < 4; ++r) {
                    float p0 = __expf(s[2 * kp][r] - m[r]);
                    sum[r] += p0;
                    st[(4 * g + r) * STG_LD + l15] = f2bf(p0);
                    if (kp < 6) {
                        float p1 = __expf(s[2 * kp + 1][r] - m[r]);
                        sum[r] += p1;
                        st[(4 * g + r) * STG_LD + 16 + l15] = f2bf(p1);
                    } else {
                        st[(4 * g + r) * STG_LD + 16 + l15] = 0;   // padded keys
                    }
                }
                short8_t aP  = *(const short8_t*)(st + l15 * STG_LD + g * 8);
                short8_t bV0 = *(const short8_t*)(VTs + l15 * VT_LD + kp * 32 + g * 8);
                short8_t bV1 = *(const short8_t*)(VTs + (16 + l15) * VT_LD + kp * 32 + g * 8);
                o0 = __builtin_amdgcn_mfma_f32_16x16x32_bf16(aP, bV0, o0, 0, 0, 0);
                o1 = __builtin_amdgcn_mfma_f32_16x16x32_bf16(aP, bV1, o1, 0, 0, 0);
            }
            #pragma unroll
            for (int r = 0; r < 4; ++r) {
                #pragma unroll
                for (int o = 1; o < 16; o <<= 1) sum[r] += __shfl_xor(sum[r], o, 64);
            }

            // normalize, stage O chunk, accumulate proj k-slice for head h
            {
                u16* st = st0;
                #pragma unroll
                for (int r = 0; r < 4; ++r) {
                    float inv = 1.f / sum[r];
                    st[(4 * g + r) * STG_LD + l15]      = f2bf(o0[r] * inv);
                    st[(4 * g + r) * STG_LD + 16 + l15] = f2bf(o1[r] * inv);
                }
                short8_t aO = *(const short8_t*)(st + l15 * STG_LD + g * 8);
                #pragma unroll
                for (int nj = 0; nj < 6; ++nj) {
                    short8_t bw = *(const short8_t*)(pjT + (nj * 16 + l15) * 96 + h * 32 + g * 8);
                    po[im][nj] = __builtin_amdgcn_mfma_f32_16x16x32_bf16(aO, bw, po[im][nj], 0, 0, 0);
                }
            }
        }
        __syncthreads();
    }

    // ---- epilogue: bias + scatter; row-grouped stores ----
    #pragma unroll
    for (int im = 0; im < 2; ++im) {
        int mt = w + NWV * im;
        int trow = mt * 16 + 4 * g;
        #pragma unroll
        for (int r = 0; r < 4; ++r) {
            int t = trow + r;
            if (t < NT) {
                float* orow = out + (size_t)rowsL[t] * C_;
                #pragma unroll
                for (int nj = 0; nj < 6; ++nj)
                    orow[nj * 16 + l15] = po[im][nj][r] + proj_b[nj * 16 + l15];
            }
        }
    }
}

// =====================================================================
// MFMA MLP kernel: round-8 proven structure (fp32 xr, 5-phase LDS LN,
// pipelined B loads); only gelu_f + f2bf implementations swapped.
// =====================================================================
__global__ __launch_bounds__(256) void mlp_mfma_kernel(
    float* __restrict__ io,
    const u16* __restrict__ ws,
    const float* __restrict__ g1, const float* __restrict__ b1,
    const float* __restrict__ g2, const float* __restrict__ b2,
    const float* __restrict__ fc1_b, const float* __restrict__ fc2_b)
{
    __shared__ float xr[64 * 100];                      // 25,600 B (x2' fp32)
    __shared__ __align__(16) u16 yb[64 * 104];          // 13,312 B (LN2, bf16)
    __shared__ __align__(16) u16 stage[4 * 2 * 16 * STG_LD];  // 10,240 B
    __shared__ float mu[64], rs[64], mu2[64], rs2[64];

    const int tid = threadIdx.x;
    const int w = tid >> 6, l15 = (tid & 63) & 15, g = (tid & 63) >> 4;
    float* base = io + (size_t)blockIdx.x * 64 * C_;
    const u16* f1T = ws + F1T_OFF;
    const u16* f2T = ws + F2T_OFF;

    for (int i = tid; i < 64 * 96; i += 256) {
        int t = i / 96, c = i - t * 96;
        xr[t * 100 + c] = base[i];
    }
    __syncthreads();

    // LN1 stats: 4 lanes per token, 24 elems each
    {
        int t = tid >> 2, q = tid & 3;
        const float* row = xr + t * 100 + q * 24;
        float s1 = 0.f, s2 = 0.f;
        #pragma unroll
        for (int j = 0; j < 24; ++j) { float v = row[j]; s1 += v; s2 += v * v; }
        s1 += __shfl_xor(s1, 1); s2 += __shfl_xor(s2, 1);
        s1 += __shfl_xor(s1, 2); s2 += __shfl_xor(s2, 2);
        if (q == 0) {
            float m_ = s1 * (1.f / 96.f);
            mu[t] = m_;
            rs[t] = rsqrtf(s2 * (1.f / 96.f) - m_ * m_ + 1e-5f);
        }
    }
    __syncthreads();
    // x2' = x2 + LN1(x2)
    for (int i = tid; i < 64 * 96; i += 256) {
        int t = i / 96, c = i - t * 96;
        float v = xr[t * 100 + c];
        xr[t * 100 + c] = v + (v - mu[t]) * rs[t] * g1[c] + b1[c];
    }
    __syncthreads();
    // LN2 stats
    {
        int t = tid >> 2, q = tid & 3;
        const float* row = xr + t * 100 + q * 24;
        float s1 = 0.f, s2 = 0.f;
        #pragma unroll
        for (int j = 0; j < 24; ++j) { float v = row[j]; s1 += v; s2 += v * v; }
        s1 += __shfl_xor(s1, 1); s2 += __shfl_xor(s2, 1);
        s1 += __shfl_xor(s1, 2); s2 += __shfl_xor(s2, 2);
        if (q == 0) {
            float m_ = s1 * (1.f / 96.f);
            mu2[t] = m_;
            rs2[t] = rsqrtf(s2 * (1.f / 96.f) - m_ * m_ + 1e-5f);
        }
    }
    __syncthreads();
    for (int i = tid; i < 64 * 96; i += 256) {
        int t = i / 96, c = i - t * 96;
        yb[t * 104 + c] = f2bf((xr[t * 100 + c] - mu2[t]) * rs2[t] * g2[c] + b2[c]);
    }
    __syncthreads();

    // A-fragments from yb (proven layout)
    short8_t aY[3];
    #pragma unroll
    for (int ks = 0; ks < 3; ++ks)
        aY[ks] = *(const short8_t*)(yb + (w * 16 + l15) * 104 + ks * 32 + g * 8);

    f32x4 po[6];
    #pragma unroll
    for (int nj = 0; nj < 6; ++nj) po[nj] = (f32x4){0.f, 0.f, 0.f, 0.f};

    // ---- B-fragment software pipeline (proven round-8 schedule) ----
    short8_t c1[2][3], n1[2][3], c2[6];
    #pragma unroll
    for (int half = 0; half < 2; ++half)
        #pragma unroll
        for (int k2 = 0; k2 < 3; ++k2)
            c1[half][k2] = *(const short8_t*)(f1T + (half * 16 + l15) * 96 + k2 * 32 + g * 8);

    u16* const st0 = stage + w * (2 * 16 * STG_LD);
    for (int ks = 0; ks < 12; ++ks) {          // fc2 k-step = 2 fc1 N-tiles
        u16* st = st0 + (ks & 1) * (16 * STG_LD);

        // issue this-iteration fc2 B loads (latency hidden by fc1+gelu+LDS)
        #pragma unroll
        for (int nj = 0; nj < 6; ++nj)
            c2[nj] = *(const short8_t*)(f2T + (nj * 16 + l15) * 384 + ks * 32 + g * 8);
        // issue next-iteration fc1 B loads (latency hidden by whole iter)
        {
            int ksn = (ks < 11) ? ks + 1 : 11;
            #pragma unroll
            for (int half = 0; half < 2; ++half)
                #pragma unroll
                for (int k2 = 0; k2 < 3; ++k2)
                    n1[half][k2] = *(const short8_t*)(f1T + ((ksn * 2 + half) * 16 + l15) * 96 + k2 * 32 + g * 8);
        }

        // fc1 + gelu with preloaded c1
        #pragma unroll
        for (int half = 0; half < 2; ++half) {
            int ncol = (ks * 2 + half) * 16 + l15;
            f32x4 acc = {0.f, 0.f, 0.f, 0.f};
            #pragma unroll
            for (int k2 = 0; k2 < 3; ++k2)
                acc = __builtin_amdgcn_mfma_f32_16x16x32_bf16(aY[k2], c1[half][k2], acc, 0, 0, 0);
            float bias = fc1_b[ncol];
            #pragma unroll
            for (int r = 0; r < 4; ++r)
                st[(4 * g + r) * STG_LD + half * 16 + l15] = f2bf(gelu_f(acc[r] + bias));
        }
        short8_t aH = *(const short8_t*)(st + l15 * STG_LD + g * 8);
        #pragma unroll
        for (int nj = 0; nj < 6; ++nj)
            po[nj] = __builtin_amdgcn_mfma_f32_16x16x32_bf16(aH, c2[nj], po[nj], 0, 0, 0);

        // rotate pipeline
        #pragma unroll
        for (int half = 0; half < 2; ++half)
            #pragma unroll
            for (int k2 = 0; k2 < 3; ++k2)
                c1[half][k2] = n1[half][k2];
    }

    // epilogue: residual + bias, row-grouped
    {
        int trow = w * 16 + 4 * g;
        #pragma unroll
        for (int r = 0; r < 4; ++r) {
            int t = trow + r;
            #pragma unroll
            for (int nj = 0; nj < 6; ++nj) {
                int ncol = nj * 16 + l15;
                base[t * 96 + ncol] = xr[t * 100 + ncol] + po[nj][r] + fc2_b[ncol];
            }
        }
    }
}

// =====================================================================
extern "C" void kernel_launch(void* const* d_in, const int* in_sizes, int n_in,
                              void* d_out, int out_size, void* d_ws, size_t ws_size,
                              hipStream_t stream)
{
    (void)in_sizes; (void)n_in; (void)out_size; (void)ws_size;

    const float* x      = (const float*)d_in[0];
    const float* qkv_w  = (const float*)d_in[1];
    const float* qkv_b  = (const float*)d_in[2];
    const float* proj_w = (const float*)d_in[3];
    const float* proj_b = (const float*)d_in[4];
    const float* g1     = (const float*)d_in[5];
    const float* b1     = (const float*)d_in[6];
    const float* g2     = (const float*)d_in[7];
    const float* b2     = (const float*)d_in[8];
    const float* fc1_w  = (const float*)d_in[9];
    const float* fc1_b  = (const float*)d_in[10];
    const float* fc2_w  = (const float*)d_in[11];
    const float* fc2_b  = (const float*)d_in[12];
    float* out = (float*)d_out;
    u16* ws = (u16*)d_ws;

    setup_kernel<<<128, 256, 0, stream>>>(qkv_w, proj_w, fc1_w, fc2_w, ws);
    attn_mfma_kernel<<<BW, 448, 0, stream>>>(x, ws, qkv_b, proj_b, out);
    mlp_mfma_kernel<<<NTOK / 64, 256, 0, stream>>>(out, ws, g1, b1, g2, b2, fc1_b, fc2_b);
}

// Round 11
// 335.472 us; speedup vs baseline: 1.1474x; 1.0199x over previous
//
#include <hip/hip_runtime.h>
#include <hip/hip_bf16.h>

// ---- problem constants ----
#define B_     16
#define NBAND  4
#define HP     56
#define WP     56
#define C_     96
#define NHEADS 3
#define HD     32
#define NT     196                 // tokens per window
#define NTP    224                 // padded to 14x16
#define BW     1024                // windows
#define HID    384
#define NTOK   200704

typedef unsigned short u16;
typedef short s16;
typedef __attribute__((ext_vector_type(8))) s16   short8_t;  // 8 bf16 (4 VGPR)
typedef __attribute__((ext_vector_type(4))) s16   short4_t;
typedef __attribute__((ext_vector_type(4))) float f32x4;

__device__ __forceinline__ float bf2f(u16 u) {
    union { float f; unsigned int i; } x; x.i = ((unsigned int)u) << 16; return x.f;
}
// HW RNE conversion
__device__ __forceinline__ u16 f2bf(float f) {
    __hip_bfloat16 h = __float2bfloat16(f);
    union { __hip_bfloat16 h; u16 u; } c; c.h = h; return c.u;
}
// sigmoid-GELU: x * sigmoid(1.702x) (validated round 10, absmax 0.0156)
__device__ __forceinline__ float gelu_f(float a) {
    return __fdividef(a, 1.0f + __expf(-1.702f * a));
}

// ---- workspace layout (bf16 elements) ----
#define WT_OFF   0          // qkv_w^T  [288][96]
#define PJT_OFF  27648      // proj_w^T [96][96]
#define F1T_OFF  36864      // fc1_w^T  [384][96]
#define F2T_OFF  73728      // fc2_w^T  [96][384]
#define WS_ELEMS 110592     // * 2 bytes = 221,184 B

__global__ __launch_bounds__(256) void setup_kernel(
    const float* __restrict__ qkv_w, const float* __restrict__ proj_w,
    const float* __restrict__ fc1_w, const float* __restrict__ fc2_w,
    u16* __restrict__ ws)
{
    int i0 = blockIdx.x * 256 + threadIdx.x;
    int stride = gridDim.x * 256;
    for (int e = i0; e < 27648; e += stride) {          // wT[n][k] = qkv_w[k][n]
        int n = e / 96, k = e - n * 96;
        ws[WT_OFF + e] = f2bf(qkv_w[k * 288 + n]);
    }
    for (int e = i0; e < 9216; e += stride) {           // pjT[n][k]
        int n = e / 96, k = e - n * 96;
        ws[PJT_OFF + e] = f2bf(proj_w[k * 96 + n]);
    }
    for (int e = i0; e < 36864; e += stride) {          // f1T[n][k], n<384
        int n = e / 96, k = e - n * 96;
        ws[F1T_OFF + e] = f2bf(fc1_w[k * 384 + n]);
    }
    for (int e = i0; e < 36864; e += stride) {          // f2T[n][k], n<96, k<384
        int n = e / 384, k = e - n * 384;
        ws[F2T_OFF + e] = f2bf(fc2_w[k * 96 + n]);
    }
}

// =====================================================================
// MFMA attention kernel: one block per window, 7 waves (448 thr)
// (round-10 proven version, unchanged)
// =====================================================================
#define NWV    7
#define QK_LD  40    // Q/K row stride (u16): 80B -> 2-way bank alias (free)
#define VT_LD  232   // V^T row stride
#define STG_LD 40    // per-wave staging row stride

__global__ __launch_bounds__(448) void attn_mfma_kernel(
    const float* __restrict__ x,
    const u16*  __restrict__ ws,
    const float* __restrict__ qkv_b,
    const float* __restrict__ proj_b,
    float* __restrict__ out)
{
    __shared__ __align__(16) u16 Qs[NTP * QK_LD];          // 17,920 B
    __shared__ __align__(16) u16 Ks[NTP * QK_LD];          // 17,920 B
    __shared__ __align__(16) u16 VTs[HD * VT_LD];          // 14,848 B
    __shared__ __align__(16) u16 Stg[NWV * 2 * 16 * STG_LD]; // 17,920 B
    __shared__ int rowsL[NT];

    const int wi  = blockIdx.x;
    const int b   = wi >> 6, ih = (wi >> 3) & 7, iw = wi & 7;
    const int tid = threadIdx.x;
    const int w   = tid >> 6, lane = tid & 63;
    const int l15 = lane & 15, g = lane >> 4;

    // token t=(n,r,col) -> flat row; roll(-3) gather == roll(+3) scatter
    if (tid < NT) {
        int t = tid;
        int n = t / 49, rc = t - n * 49, r = rc / 7, cl = rc - r * 7;
        int hh = ih * 7 + r  + 3; if (hh >= HP) hh -= HP;
        int ww = iw * 7 + cl + 3; if (ww >= WP) ww -= WP;
        rowsL[t] = ((b * NBAND + n) * HP + hh) * WP + ww;
    }
    __syncthreads();

    const u16* wT  = ws + WT_OFF;
    const u16* pjT = ws + PJT_OFF;

    // ---- preload x A-fragments for both owned M-tiles (head-invariant) ----
    short8_t ax[2][3];
    #pragma unroll
    for (int im = 0; im < 2; ++im) {
        int mt = w + NWV * im;
        int t  = mt * 16 + l15;
        bool valid = (t < NT);
        const float* xb = x + (valid ? (size_t)rowsL[t] * C_ : 0);
        #pragma unroll
        for (int ks = 0; ks < 3; ++ks) {
            short8_t a;
            if (valid) {
                const float* p = xb + ks * 32 + g * 8;
                #pragma unroll
                for (int j = 0; j < 8; ++j) a[j] = (s16)f2bf(p[j]);
            } else {
                #pragma unroll
                for (int j = 0; j < 8; ++j) a[j] = 0;
            }
            ax[im][ks] = a;
        }
    }

    f32x4 po[2][6];                       // proj accumulators
    #pragma unroll
    for (int im = 0; im < 2; ++im)
        #pragma unroll
        for (int nj = 0; nj < 6; ++nj)
            po[im][nj] = (f32x4){0.f, 0.f, 0.f, 0.f};

    u16* const st0 = Stg + w * (2 * 16 * STG_LD);

    for (int h = 0; h < NHEADS; ++h) {
        // ---- QKV GEMM for head h ----
        #pragma unroll
        for (int im = 0; im < 2; ++im) {
            int mt = w + NWV * im;
            #pragma unroll
            for (int nj = 0; nj < 6; ++nj) {
                int mat = nj >> 1, nh = nj & 1;
                int ncol = mat * 96 + h * 32 + nh * 16 + l15;
                f32x4 acc = {0.f, 0.f, 0.f, 0.f};
                #pragma unroll
                for (int ks = 0; ks < 3; ++ks) {
                    short8_t bw = *(const short8_t*)(wT + ncol * 96 + ks * 32 + g * 8);
                    acc = __builtin_amdgcn_mfma_f32_16x16x32_bf16(ax[im][ks], bw, acc, 0, 0, 0);
                }
                float bias = qkv_b[ncol];
                int d    = nh * 16 + l15;
                int trow = mt * 16 + 4 * g;
                if (mat == 0) {
                    const float sc = 0.17677669529663687f;      // hd^-0.5 folded into Q
                    #pragma unroll
                    for (int r = 0; r < 4; ++r)
                        Qs[(trow + r) * QK_LD + d] = f2bf((acc[r] + bias) * sc);
                } else if (mat == 1) {
                    #pragma unroll
                    for (int r = 0; r < 4; ++r)
                        Ks[(trow + r) * QK_LD + d] = f2bf(acc[r] + bias);
                } else {                       // V stored transposed, b64 row-writes
                    short4_t v4;
                    #pragma unroll
                    for (int r = 0; r < 4; ++r) v4[r] = (s16)f2bf(acc[r] + bias);
                    *(short4_t*)(VTs + d * VT_LD + trow) = v4;
                }
            }
        }
        __syncthreads();

        // ---- attention + per-head proj accumulate ----
        #pragma unroll
        for (int im = 0; im < 2; ++im) {
            int mt = w + NWV * im;
            short8_t aQ = *(const short8_t*)(Qs + (mt * 16 + l15) * QK_LD + g * 8);
            f32x4 s[13];
            #pragma unroll
            for (int kt = 0; kt < 13; ++kt) {
                short8_t bK = *(const short8_t*)(Ks + (kt * 16 + l15) * QK_LD + g * 8);
                f32x4 z = {0.f, 0.f, 0.f, 0.f};
                s[kt] = __builtin_amdgcn_mfma_f32_16x16x32_bf16(aQ, bK, z, 0, 0, 0);
            }
            if (l15 >= 4) {                   // keys 192+l15 >= 196 invalid
                #pragma unroll
                for (int r = 0; r < 4; ++r) s[12][r] = -1e30f;
            }
            float m[4], sum[4];
            #pragma unroll
            for (int r = 0; r < 4; ++r) {
                float mm = s[0][r];
                #pragma unroll
                for (int kt = 1; kt < 13; ++kt) mm = fmaxf(mm, s[kt][r]);
                #pragma unroll
                for (int o = 1; o < 16; o <<= 1) mm = fmaxf(mm, __shfl_xor(mm, o, 64));
                m[r] = mm;
                sum[r] = 0.f;
            }

            // PV chunked: per kp stage 16x32 of P, read A-frag, 2 MFMA
            f32x4 o0 = {0.f,0.f,0.f,0.f}, o1 = {0.f,0.f,0.f,0.f};
            #pragma unroll
            for (int kp = 0; kp < 7; ++kp) {
                u16* st = st0 + (kp & 1) * (16 * STG_LD);
                #pragma unroll
                for (int r = 0; r < 4; ++r) {
                    float p0 = __expf(s[2 * kp][r] - m[r]);
                    sum[r] += p0;
                    st[(4 * g + r) * STG_LD + l15] = f2bf(p0);
                    if (kp < 6) {
                        float p1 = __expf(s[2 * kp + 1][r] - m[r]);
                        sum[r] += p1;
                        st[(4 * g + r) * STG_LD + 16 + l15] = f2bf(p1);
                    } else {
                        st[(4 * g + r) * STG_LD + 16 + l15] = 0;   // padded keys
                    }
                }
                short8_t aP  = *(const short8_t*)(st + l15 * STG_LD + g * 8);
                short8_t bV0 = *(const short8_t*)(VTs + l15 * VT_LD + kp * 32 + g * 8);
                short8_t bV1 = *(const short8_t*)(VTs + (16 + l15) * VT_LD + kp * 32 + g * 8);
                o0 = __builtin_amdgcn_mfma_f32_16x16x32_bf16(aP, bV0, o0, 0, 0, 0);
                o1 = __builtin_amdgcn_mfma_f32_16x16x32_bf16(aP, bV1, o1, 0, 0, 0);
            }
            #pragma unroll
            for (int r = 0; r < 4; ++r) {
                #pragma unroll
                for (int o = 1; o < 16; o <<= 1) sum[r] += __shfl_xor(sum[r], o, 64);
            }

            // normalize, stage O chunk, accumulate proj k-slice for head h
            {
                u16* st = st0;
                #pragma unroll
                for (int r = 0; r < 4; ++r) {
                    float inv = 1.f / sum[r];
                    st[(4 * g + r) * STG_LD + l15]      = f2bf(o0[r] * inv);
                    st[(4 * g + r) * STG_LD + 16 + l15] = f2bf(o1[r] * inv);
                }
                short8_t aO = *(const short8_t*)(st + l15 * STG_LD + g * 8);
                #pragma unroll
                for (int nj = 0; nj < 6; ++nj) {
                    short8_t bw = *(const short8_t*)(pjT + (nj * 16 + l15) * 96 + h * 32 + g * 8);
                    po[im][nj] = __builtin_amdgcn_mfma_f32_16x16x32_bf16(aO, bw, po[im][nj], 0, 0, 0);
                }
            }
        }
        __syncthreads();
    }

    // ---- epilogue: bias + scatter; row-grouped stores ----
    #pragma unroll
    for (int im = 0; im < 2; ++im) {
        int mt = w + NWV * im;
        int trow = mt * 16 + 4 * g;
        #pragma unroll
        for (int r = 0; r < 4; ++r) {
            int t = trow + r;
            if (t < NT) {
                float* orow = out + (size_t)rowsL[t] * C_;
                #pragma unroll
                for (int nj = 0; nj < 6; ++nj)
                    orow[nj * 16 + l15] = po[im][nj][r] + proj_b[nj * 16 + l15];
            }
        }
    }
}

// =====================================================================
// MFMA MLP kernel: round-10 proven structure; hot loop restructured as
// a 1-stage software pipeline over ks: fc2(ks) consumes stage[ks&1]
// while fc1(ks+1)+gelu fills stage[(ks+1)&1]. Identical ops & rounding.
// =====================================================================
__global__ __launch_bounds__(256) void mlp_mfma_kernel(
    float* __restrict__ io,
    const u16* __restrict__ ws,
    const float* __restrict__ g1, const float* __restrict__ b1,
    const float* __restrict__ g2, const float* __restrict__ b2,
    const float* __restrict__ fc1_b, const float* __restrict__ fc2_b)
{
    __shared__ float xr[64 * 100];                      // 25,600 B (x2' fp32)
    __shared__ __align__(16) u16 yb[64 * 104];          // 13,312 B (LN2, bf16)
    __shared__ __align__(16) u16 stage[4 * 2 * 16 * STG_LD];  // 10,240 B
    __shared__ float mu[64], rs[64], mu2[64], rs2[64];

    const int tid = threadIdx.x;
    const int w = tid >> 6, l15 = (tid & 63) & 15, g = (tid & 63) >> 4;
    float* base = io + (size_t)blockIdx.x * 64 * C_;
    const u16* f1T = ws + F1T_OFF;
    const u16* f2T = ws + F2T_OFF;

    for (int i = tid; i < 64 * 96; i += 256) {
        int t = i / 96, c = i - t * 96;
        xr[t * 100 + c] = base[i];
    }
    __syncthreads();

    // LN1 stats: 4 lanes per token, 24 elems each
    {
        int t = tid >> 2, q = tid & 3;
        const float* row = xr + t * 100 + q * 24;
        float s1 = 0.f, s2 = 0.f;
        #pragma unroll
        for (int j = 0; j < 24; ++j) { float v = row[j]; s1 += v; s2 += v * v; }
        s1 += __shfl_xor(s1, 1); s2 += __shfl_xor(s2, 1);
        s1 += __shfl_xor(s1, 2); s2 += __shfl_xor(s2, 2);
        if (q == 0) {
            float m_ = s1 * (1.f / 96.f);
            mu[t] = m_;
            rs[t] = rsqrtf(s2 * (1.f / 96.f) - m_ * m_ + 1e-5f);
        }
    }
    __syncthreads();
    // x2' = x2 + LN1(x2)
    for (int i = tid; i < 64 * 96; i += 256) {
        int t = i / 96, c = i - t * 96;
        float v = xr[t * 100 + c];
        xr[t * 100 + c] = v + (v - mu[t]) * rs[t] * g1[c] + b1[c];
    }
    __syncthreads();
    // LN2 stats
    {
        int t = tid >> 2, q = tid & 3;
        const float* row = xr + t * 100 + q * 24;
        float s1 = 0.f, s2 = 0.f;
        #pragma unroll
        for (int j = 0; j < 24; ++j) { float v = row[j]; s1 += v; s2 += v * v; }
        s1 += __shfl_xor(s1, 1); s2 += __shfl_xor(s2, 1);
        s1 += __shfl_xor(s1, 2); s2 += __shfl_xor(s2, 2);
        if (q == 0) {
            float m_ = s1 * (1.f / 96.f);
            mu2[t] = m_;
            rs2[t] = rsqrtf(s2 * (1.f / 96.f) - m_ * m_ + 1e-5f);
        }
    }
    __syncthreads();
    for (int i = tid; i < 64 * 96; i += 256) {
        int t = i / 96, c = i - t * 96;
        yb[t * 104 + c] = f2bf((xr[t * 100 + c] - mu2[t]) * rs2[t] * g2[c] + b2[c]);
    }
    __syncthreads();

    // A-fragments from yb (proven layout)
    short8_t aY[3];
    #pragma unroll
    for (int ks = 0; ks < 3; ++ks)
        aY[ks] = *(const short8_t*)(yb + (w * 16 + l15) * 104 + ks * 32 + g * 8);

    f32x4 po[6];
    #pragma unroll
    for (int nj = 0; nj < 6; ++nj) po[nj] = (f32x4){0.f, 0.f, 0.f, 0.f};

    u16* const st0 = stage + w * (2 * 16 * STG_LD);

    // fc1(ks)+gelu into the given stage buffer, using preloaded weights cw
    short8_t c1[2][3];
    auto fc1_gelu = [&](int ks, u16* st) {
        #pragma unroll
        for (int half = 0; half < 2; ++half) {
            int ncol = (ks * 2 + half) * 16 + l15;
            f32x4 acc = {0.f, 0.f, 0.f, 0.f};
            #pragma unroll
            for (int k2 = 0; k2 < 3; ++k2)
                acc = __builtin_amdgcn_mfma_f32_16x16x32_bf16(aY[k2], c1[half][k2], acc, 0, 0, 0);
            float bias = fc1_b[ncol];
            #pragma unroll
            for (int r = 0; r < 4; ++r)
                st[(4 * g + r) * STG_LD + half * 16 + l15] = f2bf(gelu_f(acc[r] + bias));
        }
    };
    auto load_c1 = [&](int ks) {
        #pragma unroll
        for (int half = 0; half < 2; ++half)
            #pragma unroll
            for (int k2 = 0; k2 < 3; ++k2)
                c1[half][k2] = *(const short8_t*)(f1T + ((ks * 2 + half) * 16 + l15) * 96 + k2 * 32 + g * 8);
    };

    // ---- prologue: fill stage[0] with fc1(0) ----
    load_c1(0);
    fc1_gelu(0, st0);
    load_c1(1);

    // ---- pipelined main loop: fc2(ks) overlaps fc1(ks+1) ----
    #pragma unroll
    for (int ks = 0; ks < 12; ++ks) {
        u16* stc = st0 + (ks & 1) * (16 * STG_LD);
        u16* stn = st0 + ((ks + 1) & 1) * (16 * STG_LD);

        // fc2 weights for current ks (L2 latency hidden by fc1(ks+1))
        short8_t c2[6];
        #pragma unroll
        for (int nj = 0; nj < 6; ++nj)
            c2[nj] = *(const short8_t*)(f2T + (nj * 16 + l15) * 384 + ks * 32 + g * 8);

        // issue aH read for current ks early
        short8_t aH = *(const short8_t*)(stc + l15 * STG_LD + g * 8);

        // fill next stage buffer (independent of aH/c2 consumers)
        if (ks < 11) {
            fc1_gelu(ks + 1, stn);
            if (ks < 10) load_c1(ks + 2);
        }

        // fc2 accumulate
        #pragma unroll
        for (int nj = 0; nj < 6; ++nj)
            po[nj] = __builtin_amdgcn_mfma_f32_16x16x32_bf16(aH, c2[nj], po[nj], 0, 0, 0);
    }

    // epilogue: residual + bias, row-grouped
    {
        int trow = w * 16 + 4 * g;
        #pragma unroll
        for (int r = 0; r < 4; ++r) {
            int t = trow + r;
            #pragma unroll
            for (int nj = 0; nj < 6; ++nj) {
                int ncol = nj * 16 + l15;
                base[t * 96 + ncol] = xr[t * 100 + ncol] + po[nj][r] + fc2_b[ncol];
            }
        }
    }
}

// =====================================================================
extern "C" void kernel_launch(void* const* d_in, const int* in_sizes, int n_in,
                              void* d_out, int out_size, void* d_ws, size_t ws_size,
                              hipStream_t stream)
{
    (void)in_sizes; (void)n_in; (void)out_size; (void)ws_size;

    const float* x      = (const float*)d_in[0];
    const float* qkv_w  = (const float*)d_in[1];
    const float* qkv_b  = (const float*)d_in[2];
    const float* proj_w = (const float*)d_in[3];
    const float* proj_b = (const float*)d_in[4];
    const float* g1     = (const float*)d_in[5];
    const float* b1     = (const float*)d_in[6];
    const float* g2     = (const float*)d_in[7];
    const float* b2     = (const float*)d_in[8];
    const float* fc1_w  = (const float*)d_in[9];
    const float* fc1_b  = (const float*)d_in[10];
    const float* fc2_w  = (const float*)d_in[11];
    const float* fc2_b  = (const float*)d_in[12];
    float* out = (float*)d_out;
    u16* ws = (u16*)d_ws;

    setup_kernel<<<128, 256, 0, stream>>>(qkv_w, proj_w, fc1_w, fc2_w, ws);
    attn_mfma_kernel<<<BW, 448, 0, stream>>>(x, ws, qkv_b, proj_b, out);
    mlp_mfma_kernel<<<NTOK / 64, 256, 0, stream>>>(out, ws, g1, b1, g2, b2, fc1_b, fc2_b);
}

// Round 12
// 277.758 us; speedup vs baseline: 1.3858x; 1.2078x over previous
//
#include <hip/hip_runtime.h>
#include <hip/hip_bf16.h>

// ---- problem constants ----
#define B_     16
#define NBAND  4
#define HP     56
#define WP     56
#define C_     96
#define NHEADS 3
#define HD     32
#define NT     196                 // tokens per window
#define NTP    224                 // padded to 14x16
#define BW     1024                // windows
#define HID    384
#define NTOK   200704

typedef unsigned short u16;
typedef short s16;
typedef __attribute__((ext_vector_type(8))) s16   short8_t;  // 8 bf16 (4 VGPR)
typedef __attribute__((ext_vector_type(4))) s16   short4_t;
typedef __attribute__((ext_vector_type(4))) float f32x4;

__device__ __forceinline__ float bf2f(u16 u) {
    union { float f; unsigned int i; } x; x.i = ((unsigned int)u) << 16; return x.f;
}
// HW RNE conversion
__device__ __forceinline__ u16 f2bf(float f) {
    __hip_bfloat16 h = __float2bfloat16(f);
    union { __hip_bfloat16 h; u16 u; } c; c.h = h; return c.u;
}
// sigmoid-GELU: x * sigmoid(1.702x) (validated round 10, absmax 0.0156)
__device__ __forceinline__ float gelu_f(float a) {
    return __fdividef(a, 1.0f + __expf(-1.702f * a));
}

// ---- workspace layout (bf16 elements) ----
#define WT_OFF   0          // qkv_w^T  [288][96]
#define PJT_OFF  27648      // proj_w^T [96][96]
#define F1T_OFF  36864      // fc1_w^T  [384][96]
#define F2T_OFF  73728      // fc2_w^T  [96][384]
#define WS_ELEMS 110592     // * 2 bytes = 221,184 B

__global__ __launch_bounds__(256) void setup_kernel(
    const float* __restrict__ qkv_w, const float* __restrict__ proj_w,
    const float* __restrict__ fc1_w, const float* __restrict__ fc2_w,
    u16* __restrict__ ws)
{
    int i0 = blockIdx.x * 256 + threadIdx.x;
    int stride = gridDim.x * 256;
    for (int e = i0; e < 27648; e += stride) {          // wT[n][k] = qkv_w[k][n]
        int n = e / 96, k = e - n * 96;
        ws[WT_OFF + e] = f2bf(qkv_w[k * 288 + n]);
    }
    for (int e = i0; e < 9216; e += stride) {           // pjT[n][k]
        int n = e / 96, k = e - n * 96;
        ws[PJT_OFF + e] = f2bf(proj_w[k * 96 + n]);
    }
    for (int e = i0; e < 36864; e += stride) {          // f1T[n][k], n<384
        int n = e / 96, k = e - n * 96;
        ws[F1T_OFF + e] = f2bf(fc1_w[k * 384 + n]);
    }
    for (int e = i0; e < 36864; e += stride) {          // f2T[n][k], n<96, k<384
        int n = e / 384, k = e - n * 384;
        ws[F2T_OFF + e] = f2bf(fc2_w[k * 96 + n]);
    }
}

// =====================================================================
// FUSED kernel: window attention + LN/MLP, one block per window, 7 waves.
// Attention section is the proven round-10/11 code. After the head loop,
// Qs|Ks|VTs (dead) are aliased as X2[224x104] bf16 holding x2 -> x2';
// LN phases use the proven r8/r9 LDS patterns; MLP hot loop is the
// proven r8 pipelined loop with both M-tiles interleaved per k-step.
// LDS ~73KB -> 2 blocks/CU.
// =====================================================================
#define NWV    7
#define QK_LD  40    // Q/K row stride (u16)
#define VT_LD  232   // V^T row stride
#define STG_LD 40    // per-wave staging row stride
#define X2_LD  104   // x2 row stride (u16)
#define ABUF_ELEMS (2 * NTP * QK_LD + HD * VT_LD)   // 25,344 u16 = 50,688 B

__global__ __launch_bounds__(448) void fused_kernel(
    const float* __restrict__ x,
    const u16*  __restrict__ ws,
    const float* __restrict__ qkv_b,
    const float* __restrict__ proj_b,
    const float* __restrict__ g1, const float* __restrict__ b1,
    const float* __restrict__ g2, const float* __restrict__ b2,
    const float* __restrict__ fc1_b, const float* __restrict__ fc2_b,
    float* __restrict__ out)
{
    __shared__ __align__(16) u16 ABuf[ABUF_ELEMS];          // Qs|Ks|VTs, later X2
    __shared__ __align__(16) u16 Stg[NWV * 2 * 16 * STG_LD]; // 17,920 B
    __shared__ int rowsL[NT];
    __shared__ float muA[NTP], rsA[NTP], mu2[NTP], rs2[NTP]; // 3,584 B

    u16* const Qs  = ABuf;
    u16* const Ks  = ABuf + NTP * QK_LD;
    u16* const VTs = ABuf + 2 * NTP * QK_LD;
    u16* const X2  = ABuf;                     // alias, used after head loop

    const int wi  = blockIdx.x;
    const int b   = wi >> 6, ih = (wi >> 3) & 7, iw = wi & 7;
    const int tid = threadIdx.x;
    const int w   = tid >> 6, lane = tid & 63;
    const int l15 = lane & 15, g = lane >> 4;

    // token t=(n,r,col) -> flat row; roll(-3) gather == roll(+3) scatter
    if (tid < NT) {
        int t = tid;
        int n = t / 49, rc = t - n * 49, r = rc / 7, cl = rc - r * 7;
        int hh = ih * 7 + r  + 3; if (hh >= HP) hh -= HP;
        int ww = iw * 7 + cl + 3; if (ww >= WP) ww -= WP;
        rowsL[t] = ((b * NBAND + n) * HP + hh) * WP + ww;
    }
    __syncthreads();

    const u16* wT  = ws + WT_OFF;
    const u16* pjT = ws + PJT_OFF;
    const u16* f1T = ws + F1T_OFF;
    const u16* f2T = ws + F2T_OFF;

    // ---- preload x A-fragments for both owned M-tiles (head-invariant) ----
    short8_t ax[2][3];
    #pragma unroll
    for (int im = 0; im < 2; ++im) {
        int mt = w + NWV * im;
        int t  = mt * 16 + l15;
        bool valid = (t < NT);
        const float* xb = x + (valid ? (size_t)rowsL[t] * C_ : 0);
        #pragma unroll
        for (int ks = 0; ks < 3; ++ks) {
            short8_t a;
            if (valid) {
                const float* p = xb + ks * 32 + g * 8;
                #pragma unroll
                for (int j = 0; j < 8; ++j) a[j] = (s16)f2bf(p[j]);
            } else {
                #pragma unroll
                for (int j = 0; j < 8; ++j) a[j] = 0;
            }
            ax[im][ks] = a;
        }
    }

    f32x4 po[2][6];                       // proj accumulators
    #pragma unroll
    for (int im = 0; im < 2; ++im)
        #pragma unroll
        for (int nj = 0; nj < 6; ++nj)
            po[im][nj] = (f32x4){0.f, 0.f, 0.f, 0.f};

    u16* const st0 = Stg + w * (2 * 16 * STG_LD);

    for (int h = 0; h < NHEADS; ++h) {
        // ---- QKV GEMM for head h (proven) ----
        #pragma unroll
        for (int im = 0; im < 2; ++im) {
            int mt = w + NWV * im;
            #pragma unroll
            for (int nj = 0; nj < 6; ++nj) {
                int mat = nj >> 1, nh = nj & 1;
                int ncol = mat * 96 + h * 32 + nh * 16 + l15;
                f32x4 acc = {0.f, 0.f, 0.f, 0.f};
                #pragma unroll
                for (int ks = 0; ks < 3; ++ks) {
                    short8_t bw = *(const short8_t*)(wT + ncol * 96 + ks * 32 + g * 8);
                    acc = __builtin_amdgcn_mfma_f32_16x16x32_bf16(ax[im][ks], bw, acc, 0, 0, 0);
                }
                float bias = qkv_b[ncol];
                int d    = nh * 16 + l15;
                int trow = mt * 16 + 4 * g;
                if (mat == 0) {
                    const float sc = 0.17677669529663687f;      // hd^-0.5 folded into Q
                    #pragma unroll
                    for (int r = 0; r < 4; ++r)
                        Qs[(trow + r) * QK_LD + d] = f2bf((acc[r] + bias) * sc);
                } else if (mat == 1) {
                    #pragma unroll
                    for (int r = 0; r < 4; ++r)
                        Ks[(trow + r) * QK_LD + d] = f2bf(acc[r] + bias);
                } else {                       // V stored transposed
                    short4_t v4;
                    #pragma unroll
                    for (int r = 0; r < 4; ++r) v4[r] = (s16)f2bf(acc[r] + bias);
                    *(short4_t*)(VTs + d * VT_LD + trow) = v4;
                }
            }
        }
        __syncthreads();

        // ---- attention + per-head proj accumulate (proven) ----
        #pragma unroll
        for (int im = 0; im < 2; ++im) {
            int mt = w + NWV * im;
            short8_t aQ = *(const short8_t*)(Qs + (mt * 16 + l15) * QK_LD + g * 8);
            f32x4 s[13];
            #pragma unroll
            for (int kt = 0; kt < 13; ++kt) {
                short8_t bK = *(const short8_t*)(Ks + (kt * 16 + l15) * QK_LD + g * 8);
                f32x4 z = {0.f, 0.f, 0.f, 0.f};
                s[kt] = __builtin_amdgcn_mfma_f32_16x16x32_bf16(aQ, bK, z, 0, 0, 0);
            }
            if (l15 >= 4) {                   // keys 192+l15 >= 196 invalid
                #pragma unroll
                for (int r = 0; r < 4; ++r) s[12][r] = -1e30f;
            }
            float m[4], sum[4];
            #pragma unroll
            for (int r = 0; r < 4; ++r) {
                float mm = s[0][r];
                #pragma unroll
                for (int kt = 1; kt < 13; ++kt) mm = fmaxf(mm, s[kt][r]);
                #pragma unroll
                for (int o = 1; o < 16; o <<= 1) mm = fmaxf(mm, __shfl_xor(mm, o, 64));
                m[r] = mm;
                sum[r] = 0.f;
            }

            f32x4 o0 = {0.f,0.f,0.f,0.f}, o1 = {0.f,0.f,0.f,0.f};
            #pragma unroll
            for (int kp = 0; kp < 7; ++kp) {
                u16* st = st0 + (kp & 1) * (16 * STG_LD);
                #pragma unroll
                for (int r = 0; r < 4; ++r) {
                    float p0 = __expf(s[2 * kp][r] - m[r]);
                    sum[r] += p0;
                    st[(4 * g + r) * STG_LD + l15] = f2bf(p0);
                    if (kp < 6) {
                        float p1 = __expf(s[2 * kp + 1][r] - m[r]);
                        sum[r] += p1;
                        st[(4 * g + r) * STG_LD + 16 + l15] = f2bf(p1);
                    } else {
                        st[(4 * g + r) * STG_LD + 16 + l15] = 0;   // padded keys
                    }
                }
                short8_t aP  = *(const short8_t*)(st + l15 * STG_LD + g * 8);
                short8_t bV0 = *(const short8_t*)(VTs + l15 * VT_LD + kp * 32 + g * 8);
                short8_t bV1 = *(const short8_t*)(VTs + (16 + l15) * VT_LD + kp * 32 + g * 8);
                o0 = __builtin_amdgcn_mfma_f32_16x16x32_bf16(aP, bV0, o0, 0, 0, 0);
                o1 = __builtin_amdgcn_mfma_f32_16x16x32_bf16(aP, bV1, o1, 0, 0, 0);
            }
            #pragma unroll
            for (int r = 0; r < 4; ++r) {
                #pragma unroll
                for (int o = 1; o < 16; o <<= 1) sum[r] += __shfl_xor(sum[r], o, 64);
            }

            {
                u16* st = st0;
                #pragma unroll
                for (int r = 0; r < 4; ++r) {
                    float inv = 1.f / sum[r];
                    st[(4 * g + r) * STG_LD + l15]      = f2bf(o0[r] * inv);
                    st[(4 * g + r) * STG_LD + 16 + l15] = f2bf(o1[r] * inv);
                }
                short8_t aO = *(const short8_t*)(st + l15 * STG_LD + g * 8);
                #pragma unroll
                for (int nj = 0; nj < 6; ++nj) {
                    short8_t bw = *(const short8_t*)(pjT + (nj * 16 + l15) * 96 + h * 32 + g * 8);
                    po[im][nj] = __builtin_amdgcn_mfma_f32_16x16x32_bf16(aO, bw, po[im][nj], 0, 0, 0);
                }
            }
        }
        __syncthreads();
    }
    // Qs/Ks/VTs now dead; ABuf becomes X2.

    // ---- x2 = attn_out + proj_b  -> X2 (bf16, C-layout scatter) ----
    #pragma unroll
    for (int im = 0; im < 2; ++im) {
        int mt = w + NWV * im;
        int trow = mt * 16 + 4 * g;
        #pragma unroll
        for (int nj = 0; nj < 6; ++nj) {
            int ncol = nj * 16 + l15;
            float bias = proj_b[ncol];
            #pragma unroll
            for (int r = 0; r < 4; ++r)
                X2[(trow + r) * X2_LD + ncol] = f2bf(po[im][nj][r] + bias);
        }
    }
    __syncthreads();

    // ---- LN1 stats over x2 (proven 4-lane shfl pattern, 2 reps) ----
    #pragma unroll
    for (int rep = 0; rep < 2; ++rep) {
        int t = rep * 112 + (tid >> 2), q = tid & 3;
        const u16* row = X2 + t * X2_LD + q * 24;
        float s1 = 0.f, s2 = 0.f;
        #pragma unroll
        for (int j = 0; j < 24; ++j) { float v = bf2f(row[j]); s1 += v; s2 += v * v; }
        s1 += __shfl_xor(s1, 1); s2 += __shfl_xor(s2, 1);
        s1 += __shfl_xor(s1, 2); s2 += __shfl_xor(s2, 2);
        if (q == 0) {
            float m_ = s1 * (1.f / 96.f);
            muA[t] = m_;
            rsA[t] = rsqrtf(s2 * (1.f / 96.f) - m_ * m_ + 1e-5f);
        }
    }
    __syncthreads();

    // ---- x2' = x2 + LN1(x2), in place ----
    for (int i = tid; i < NTP * 96; i += 448) {
        int t = i / 96, c = i - t * 96;
        float v = bf2f(X2[t * X2_LD + c]);
        X2[t * X2_LD + c] = f2bf(v + (v - muA[t]) * rsA[t] * g1[c] + b1[c]);
    }
    __syncthreads();

    // ---- LN2 stats over x2' ----
    #pragma unroll
    for (int rep = 0; rep < 2; ++rep) {
        int t = rep * 112 + (tid >> 2), q = tid & 3;
        const u16* row = X2 + t * X2_LD + q * 24;
        float s1 = 0.f, s2 = 0.f;
        #pragma unroll
        for (int j = 0; j < 24; ++j) { float v = bf2f(row[j]); s1 += v; s2 += v * v; }
        s1 += __shfl_xor(s1, 1); s2 += __shfl_xor(s2, 1);
        s1 += __shfl_xor(s1, 2); s2 += __shfl_xor(s2, 2);
        if (q == 0) {
            float m_ = s1 * (1.f / 96.f);
            mu2[t] = m_;
            rs2[t] = rsqrtf(s2 * (1.f / 96.f) - m_ * m_ + 1e-5f);
        }
    }
    __syncthreads();

    // ---- aY fragments: LN2 affine on A-frag reads of X2 ----
    short8_t aYv[2][3];
    #pragma unroll
    for (int im = 0; im < 2; ++im) {
        int row = (w + NWV * im) * 16 + l15;
        float m2v = mu2[row], r2v = rs2[row];
        #pragma unroll
        for (int ks = 0; ks < 3; ++ks) {
            short8_t xv = *(const short8_t*)(X2 + row * X2_LD + ks * 32 + g * 8);
            short8_t a;
            #pragma unroll
            for (int j = 0; j < 8; ++j) {
                int c = ks * 32 + g * 8 + j;
                a[j] = (s16)f2bf((bf2f((u16)xv[j]) - m2v) * r2v * g2[c] + b2[c]);
            }
            aYv[im][ks] = a;
        }
    }

    // ---- MLP hot loop: both M-tiles per k-step, shared weights ----
    f32x4 p2[2][6];
    #pragma unroll
    for (int im = 0; im < 2; ++im)
        #pragma unroll
        for (int nj = 0; nj < 6; ++nj) p2[im][nj] = (f32x4){0.f, 0.f, 0.f, 0.f};

    short8_t c1[2][3], n1[2][3];
    #pragma unroll
    for (int half = 0; half < 2; ++half)
        #pragma unroll
        for (int k2 = 0; k2 < 3; ++k2)
            c1[half][k2] = *(const short8_t*)(f1T + (half * 16 + l15) * 96 + k2 * 32 + g * 8);

    u16* const stA = st0;
    u16* const stB = st0 + 16 * STG_LD;

    for (int ks = 0; ks < 12; ++ks) {
        // fc2 weights for this ks (shared by both tiles)
        short8_t c2[6];
        #pragma unroll
        for (int nj = 0; nj < 6; ++nj)
            c2[nj] = *(const short8_t*)(f2T + (nj * 16 + l15) * 384 + ks * 32 + g * 8);

        // fc1 + gelu for both tiles into their stage buffers
        #pragma unroll
        for (int im = 0; im < 2; ++im) {
            u16* st = (im == 0) ? stA : stB;
            #pragma unroll
            for (int half = 0; half < 2; ++half) {
                int ncol = (ks * 2 + half) * 16 + l15;
                f32x4 acc = {0.f, 0.f, 0.f, 0.f};
                #pragma unroll
                for (int k2 = 0; k2 < 3; ++k2)
                    acc = __builtin_amdgcn_mfma_f32_16x16x32_bf16(aYv[im][k2], c1[half][k2], acc, 0, 0, 0);
                float bias = fc1_b[ncol];
                #pragma unroll
                for (int r = 0; r < 4; ++r)
                    st[(4 * g + r) * STG_LD + half * 16 + l15] = f2bf(gelu_f(acc[r] + bias));
            }
        }

        // prefetch next-iteration fc1 weights (latency hides under fc2)
        if (ks < 11) {
            #pragma unroll
            for (int half = 0; half < 2; ++half)
                #pragma unroll
                for (int k2 = 0; k2 < 3; ++k2)
                    n1[half][k2] = *(const short8_t*)(f1T + (((ks + 1) * 2 + half) * 16 + l15) * 96 + k2 * 32 + g * 8);
        }

        short8_t aH0 = *(const short8_t*)(stA + l15 * STG_LD + g * 8);
        short8_t aH1 = *(const short8_t*)(stB + l15 * STG_LD + g * 8);
        #pragma unroll
        for (int nj = 0; nj < 6; ++nj) {
            p2[0][nj] = __builtin_amdgcn_mfma_f32_16x16x32_bf16(aH0, c2[nj], p2[0][nj], 0, 0, 0);
            p2[1][nj] = __builtin_amdgcn_mfma_f32_16x16x32_bf16(aH1, c2[nj], p2[1][nj], 0, 0, 0);
        }

        #pragma unroll
        for (int half = 0; half < 2; ++half)
            #pragma unroll
            for (int k2 = 0; k2 < 3; ++k2)
                c1[half][k2] = n1[half][k2];
    }

    // ---- final: out = x2' + fc2_out + fc2_b, scatter via rowsL ----
    #pragma unroll
    for (int im = 0; im < 2; ++im) {
        int mt = w + NWV * im;
        int trow = mt * 16 + 4 * g;
        #pragma unroll
        for (int r = 0; r < 4; ++r) {
            int t = trow + r;
            if (t < NT) {
                float* orow = out + (size_t)rowsL[t] * C_;
                #pragma unroll
                for (int nj = 0; nj < 6; ++nj) {
                    int ncol = nj * 16 + l15;
                    orow[ncol] = bf2f(X2[t * X2_LD + ncol]) + p2[im][nj][r] + fc2_b[ncol];
                }
            }
        }
    }
}

// =====================================================================
extern "C" void kernel_launch(void* const* d_in, const int* in_sizes, int n_in,
                              void* d_out, int out_size, void* d_ws, size_t ws_size,
                              hipStream_t stream)
{
    (void)in_sizes; (void)n_in; (void)out_size; (void)ws_size;

    const float* x      = (const float*)d_in[0];
    const float* qkv_w  = (const float*)d_in[1];
    const float* qkv_b  = (const float*)d_in[2];
    const float* proj_w = (const float*)d_in[3];
    const float* proj_b = (const float*)d_in[4];
    const float* g1     = (const float*)d_in[5];
    const float* b1     = (const float*)d_in[6];
    const float* g2     = (const float*)d_in[7];
    const float* b2     = (const float*)d_in[8];
    const float* fc1_w  = (const float*)d_in[9];
    const float* fc1_b  = (const float*)d_in[10];
    const float* fc2_w  = (const float*)d_in[11];
    const float* fc2_b  = (const float*)d_in[12];
    float* out = (float*)d_out;
    u16* ws = (u16*)d_ws;

    setup_kernel<<<128, 256, 0, stream>>>(qkv_w, proj_w, fc1_w, fc2_w, ws);
    fused_kernel<<<BW, 448, 0, stream>>>(x, ws, qkv_b, proj_b,
                                         g1, b1, g2, b2, fc1_b, fc2_b, out);
}